// Round 3
// baseline (675.212 us; speedup 1.0000x reference)
//
#include <hip/hip_runtime.h>

#define N_USERS 100000
#define N_ITEMS 50000
#define N_NODES 150000
#define N_EDGES 2400000
#define EMB 64
#define LEAKY 0.3f

#define SCAN_CHUNK 1024
#define NBLK ((N_NODES + SCAN_CHUNK - 1) / SCAN_CHUNK)   // 147

#define RB_SHIFT 8                                        // 256 rows / bucket
#define NBKT ((N_NODES + (1 << RB_SHIFT) - 1) >> RB_SHIFT) // 586
#define L1_CHUNK 8192                                     // edges per partition block
#define NBLK_L1 ((N_EDGES + L1_CHUNK - 1) / L1_CHUNK)     // 293

// ===========================================================================
// CSR build: histogram -> hierarchical exclusive scan
// ===========================================================================
__global__ __launch_bounds__(256) void hist_kernel(
    const int* __restrict__ rows, int* __restrict__ cnt)
{
    const int i = blockIdx.x * 256 + threadIdx.x;
    if (i < N_EDGES) atomicAdd(&cnt[rows[i]], 1);
}

__global__ __launch_bounds__(256) void scan_partial(
    const int* __restrict__ cnt, int* __restrict__ blk_sums)
{
    __shared__ int lds[256];
    const int b = blockIdx.x, t = threadIdx.x;
    const int base = b * SCAN_CHUNK + t * 4;
    int s = 0;
    #pragma unroll
    for (int j = 0; j < 4; ++j) {
        const int idx = base + j;
        if (idx < N_NODES) s += cnt[idx];
    }
    lds[t] = s;
    __syncthreads();
    for (int off = 128; off > 0; off >>= 1) {
        if (t < off) lds[t] += lds[t + off];
        __syncthreads();
    }
    if (t == 0) blk_sums[b] = lds[0];
}

__global__ __launch_bounds__(256) void scan_blk(
    const int* __restrict__ blk_sums, int* __restrict__ blk_offs)
{
    __shared__ int lds[256];
    const int t = threadIdx.x;
    const int v = (t < NBLK) ? blk_sums[t] : 0;
    lds[t] = v;
    __syncthreads();
    for (int off = 1; off < 256; off <<= 1) {
        int x = 0;
        if (t >= off) x = lds[t - off];
        __syncthreads();
        lds[t] += x;
        __syncthreads();
    }
    if (t < NBLK) blk_offs[t] = lds[t] - v;   // exclusive
}

__global__ __launch_bounds__(256) void scan_apply(
    const int* __restrict__ cnt, const int* __restrict__ blk_offs,
    int* __restrict__ row_ptr)
{
    __shared__ int lds[256];
    const int b = blockIdx.x, t = threadIdx.x;
    const int base = b * SCAN_CHUNK + t * 4;
    int v[4];
    int s = 0;
    #pragma unroll
    for (int j = 0; j < 4; ++j) {
        const int idx = base + j;
        v[j] = (idx < N_NODES) ? cnt[idx] : 0;
        s += v[j];
    }
    lds[t] = s;
    __syncthreads();
    for (int off = 1; off < 256; off <<= 1) {
        int x = 0;
        if (t >= off) x = lds[t - off];
        __syncthreads();
        lds[t] += x;
        __syncthreads();
    }
    int run = blk_offs[b] + (lds[t] - s);
    #pragma unroll
    for (int j = 0; j < 4; ++j) {
        const int idx = base + j;
        if (idx < N_NODES) {
            row_ptr[idx] = run;
            run += v[j];
        }
    }
}

// row_ptr sentinel + bucket tails (bkt_tail[b] = row_ptr[b<<RB_SHIFT])
__global__ __launch_bounds__(256) void init_aux(
    int* __restrict__ row_ptr, int* __restrict__ bkt_tail)
{
    const int i = blockIdx.x * 256 + threadIdx.x;
    if (i == 0) row_ptr[N_NODES] = N_EDGES;
    if (i < NBKT) bkt_tail[i] = row_ptr[i << RB_SHIFT];
}

// ===========================================================================
// Two-level partition scatter.
// Level 1: bin edges into 586 buckets (chunked appends, LDS-aggregated).
// ===========================================================================
__global__ __launch_bounds__(256) void partition_l1(
    const float* __restrict__ vals, const int* __restrict__ rows,
    const int* __restrict__ cols, int* __restrict__ bkt_tail,
    float2* __restrict__ svc, int* __restrict__ srow)
{
    __shared__ int cnt[NBKT];
    __shared__ int base[NBKT];

    const int t  = threadIdx.x;
    const int e0 = blockIdx.x * L1_CHUNK;
    const int e1 = (e0 + L1_CHUNK < N_EDGES) ? e0 + L1_CHUNK : N_EDGES;

    for (int b = t; b < NBKT; b += 256) cnt[b] = 0;
    __syncthreads();

    for (int i = e0 + t; i < e1; i += 256)
        atomicAdd(&cnt[rows[i] >> RB_SHIFT], 1);
    __syncthreads();

    for (int b = t; b < NBKT; b += 256) {
        const int c = cnt[b];
        base[b] = (c > 0) ? atomicAdd(&bkt_tail[b], c) : 0;
        cnt[b] = 0;
    }
    __syncthreads();

    for (int i = e0 + t; i < e1; i += 256) {
        const int r = rows[i];
        const int b = r >> RB_SHIFT;
        const int pos = base[b] + atomicAdd(&cnt[b], 1);
        svc[pos]  = make_float2(vals[i], __int_as_float(cols[i]));
        srow[pos] = r;
    }
}

// Level 2: one block per bucket; final in-row placement via LDS heads.
// Block's writes confined to one ~32KB range -> one XCD L2 absorbs them.
__global__ __launch_bounds__(256) void place_l2(
    const int* __restrict__ row_ptr, const int* __restrict__ srow,
    const float2* __restrict__ svc, float2* __restrict__ sedge)
{
    __shared__ int h[1 << RB_SHIFT];
    const int b     = blockIdx.x;
    const int rbase = b << RB_SHIFT;
    const int t     = threadIdx.x;

    h[t] = (rbase + t < N_NODES) ? row_ptr[rbase + t] : 0;
    __syncthreads();

    const int lo = row_ptr[rbase];
    int hidx = rbase + (1 << RB_SHIFT);
    if (hidx > N_NODES) hidx = N_NODES;
    const int hi = row_ptr[hidx];

    for (int i = lo + t; i < hi; i += 256) {
        const int r    = srow[i];
        const float2 vc = svc[i];
        const int pos  = atomicAdd(&h[r - rbase], 1);
        sedge[pos] = vc;
    }
}

// ===========================================================================
// Fused pull-SpMM + dense(W^T) + activation + mean accumulation.
// One wave per row. 16-lane groups gather float4 (4 edges / VMEM instr,
// 8 edges in flight). Cross-group shfl reduce, then per-lane W-row dot.
// ===========================================================================
__device__ __forceinline__ const float* src_row(
    const float* __restrict__ src_a, const float* __restrict__ src_b, int c)
{
    if (src_b != nullptr && c >= N_USERS)
        return src_b + (size_t)(c - N_USERS) * EMB;
    return src_a + (size_t)c * EMB;
}

template <bool FIRST>
__global__ __launch_bounds__(256) void spmm_fused(
    const int* __restrict__ row_ptr,     // N_NODES+1 (sentinel)
    const float2* __restrict__ sedge,    // row-sorted (val, col)
    const float* __restrict__ src_a,     // FIRST: user_emb ; else e2 (full)
    const float* __restrict__ src_b,     // FIRST: item_emb ; else nullptr
    const float* __restrict__ W,         // [64][64] row-major
    float* __restrict__ e2out,           // FIRST only
    float* __restrict__ out)
{
    __shared__ float wLds[64 * 65];

    const int tid = threadIdx.x;
    for (int idx = tid; idx < 64 * 64; idx += 256)
        wLds[(idx >> 6) * 65 + (idx & 63)] = W[idx];
    __syncthreads();

    const int lane = tid & 63;
    const int row  = blockIdx.x * 4 + (tid >> 6);
    if (row >= N_NODES) return;

    // W row `lane` -> registers (padded LDS: conflict-free)
    float w[64];
    #pragma unroll
    for (int c = 0; c < 64; ++c) w[c] = wLds[lane * 65 + c];

    const int q = lane & 15;       // float4 slot within a row (features 4q..4q+3)
    const int g = lane >> 4;       // edge slot 0..3

    const int beg = row_ptr[row];
    const int end = row_ptr[row + 1];

    float a0 = 0.f, a1 = 0.f, a2 = 0.f, a3 = 0.f;
    int k = beg;
    for (; k + 8 <= end; k += 8) {
        const float2 eA = sedge[k + g];
        const float2 eB = sedge[k + 4 + g];
        const float4 xA = *(const float4*)(src_row(src_a, src_b, __float_as_int(eA.y)) + (q << 2));
        const float4 xB = *(const float4*)(src_row(src_a, src_b, __float_as_int(eB.y)) + (q << 2));
        a0 = fmaf(eA.x, xA.x, a0);
        a1 = fmaf(eA.x, xA.y, a1);
        a2 = fmaf(eA.x, xA.z, a2);
        a3 = fmaf(eA.x, xA.w, a3);
        a0 = fmaf(eB.x, xB.x, a0);
        a1 = fmaf(eB.x, xB.y, a1);
        a2 = fmaf(eB.x, xB.z, a2);
        a3 = fmaf(eB.x, xB.w, a3);
    }
    const int rem = end - k;
    if (g < rem) {
        const float2 e = sedge[k + g];
        const float4 x = *(const float4*)(src_row(src_a, src_b, __float_as_int(e.y)) + (q << 2));
        a0 = fmaf(e.x, x.x, a0);
        a1 = fmaf(e.x, x.y, a1);
        a2 = fmaf(e.x, x.z, a2);
        a3 = fmaf(e.x, x.w, a3);
    }
    if (g + 4 < rem) {
        const float2 e = sedge[k + 4 + g];
        const float4 x = *(const float4*)(src_row(src_a, src_b, __float_as_int(e.y)) + (q << 2));
        a0 = fmaf(e.x, x.x, a0);
        a1 = fmaf(e.x, x.y, a1);
        a2 = fmaf(e.x, x.z, a2);
        a3 = fmaf(e.x, x.w, a3);
    }

    // reduce the 4 edge-groups: lane then holds trow[4q+j] in a_j
    a0 += __shfl_xor(a0, 16); a0 += __shfl_xor(a0, 32);
    a1 += __shfl_xor(a1, 16); a1 += __shfl_xor(a1, 32);
    a2 += __shfl_xor(a2, 16); a2 += __shfl_xor(a2, 32);
    a3 += __shfl_xor(a3, 16); a3 += __shfl_xor(a3, 32);

    // dense: e1[lane] = sum_j trow[j] * W[lane][j]; trow[4qq+j] lives in lane qq
    float e1 = 0.f;
    #pragma unroll
    for (int qq = 0; qq < 16; ++qq) {
        const float t0 = __shfl(a0, qq, 64);
        const float t1 = __shfl(a1, qq, 64);
        const float t2 = __shfl(a2, qq, 64);
        const float t3 = __shfl(a3, qq, 64);
        e1 = fmaf(t0, w[qq * 4 + 0], e1);
        e1 = fmaf(t1, w[qq * 4 + 1], e1);
        e1 = fmaf(t2, w[qq * 4 + 2], e1);
        e1 = fmaf(t3, w[qq * 4 + 3], e1);
    }

    const size_t idx = (size_t)row * EMB + lane;
    if (FIRST) {
        const float e2v = (e1 >= 0.f) ? e1 : LEAKY * e1;
        const float e0v = (row < N_USERS)
                              ? src_a[idx]                                  // user_emb
                              : src_b[idx - (size_t)N_USERS * EMB];         // item_emb
        e2out[idx] = e2v;
        out[idx]   = 0.25f * (e0v + e1 + e2v);
    } else {
        out[idx] += 0.25f * e1;
    }
}

// ===========================================================================
// Fallback path (round-1 proven): atomic SpMM + separate dense stages.
// ===========================================================================
__global__ __launch_bounds__(256) void spmm_atomic(
    const float* __restrict__ vals, const int* __restrict__ rows,
    const int* __restrict__ cols, const float* __restrict__ src_a,
    const float* __restrict__ src_b, float* __restrict__ dst)
{
    const int tid  = threadIdx.x;
    const int lane = tid & 63;
    const int e    = blockIdx.x * 4 + (tid >> 6);
    if (e >= N_EDGES) return;
    const float v = vals[e];
    const int   c = cols[e];
    const int   r = rows[e];
    const float* src = src_row(src_a, src_b, c);
    unsafeAtomicAdd(&dst[(size_t)r * EMB + lane], v * src[lane]);
}

template <bool FIRST>
__global__ __launch_bounds__(256) void dense_stage(
    const float* __restrict__ t, const float* __restrict__ W,
    const float* __restrict__ user_emb, const float* __restrict__ item_emb,
    float* __restrict__ e2, float* __restrict__ out)
{
    __shared__ float wT[64][65];
    __shared__ float trow[16][64];

    const int tid = threadIdx.x;
    for (int k = tid; k < 64 * 64; k += 256) {
        const int i = k >> 6, j = k & 63;
        wT[j][i] = W[k];
    }
    const int row_base = blockIdx.x * 16;
    for (int k = tid; k < 16 * 64; k += 256) {
        const int r = k >> 6, j = k & 63;
        const int row = row_base + r;
        trow[r][j] = (row < N_NODES) ? t[(size_t)row * EMB + j] : 0.f;
    }
    __syncthreads();

    const int i  = tid & 63;
    const int r0 = tid >> 6;

    #pragma unroll
    for (int rr = 0; rr < 4; ++rr) {
        const int r   = r0 * 4 + rr;
        const int row = row_base + r;
        if (row >= N_NODES) continue;

        float acc = 0.f;
        #pragma unroll
        for (int j = 0; j < 64; ++j)
            acc = fmaf(trow[r][j], wT[j][i], acc);

        const size_t idx = (size_t)row * EMB + i;
        if (FIRST) {
            const float e1v = acc;
            const float e2v = (e1v >= 0.f) ? e1v : LEAKY * e1v;
            const float e0v = (row < N_USERS)
                                  ? user_emb[idx]
                                  : item_emb[(size_t)(row - N_USERS) * EMB + i];
            e2[idx]  = e2v;
            out[idx] = 0.25f * (e0v + e1v + e2v);
        } else {
            out[idx] += 0.25f * acc;
        }
    }
}

// ===========================================================================
extern "C" void kernel_launch(void* const* d_in, const int* in_sizes, int n_in,
                              void* d_out, int out_size, void* d_ws, size_t ws_size,
                              hipStream_t stream)
{
    const float* user_emb = (const float*)d_in[0];
    const float* item_emb = (const float*)d_in[1];
    const float* W0       = (const float*)d_in[2];
    const float* W1       = (const float*)d_in[3];
    const float* adj_vals = (const float*)d_in[4];
    const int*   adj_rows = (const int*)d_in[5];
    const int*   adj_cols = (const int*)d_in[6];
    float*       out      = (float*)d_out;

    const size_t mat_bytes  = (size_t)N_NODES * EMB * sizeof(float);   // 38.4 MB
    const size_t edge8      = (size_t)N_EDGES * sizeof(float2);        // 19.2 MB
    const size_t edge4      = (size_t)N_EDGES * sizeof(int);           //  9.6 MB
    const size_t rp_bytes   = (size_t)(N_NODES + 1) * sizeof(int);
    const size_t node_ints  = (size_t)N_NODES * sizeof(int);

    const size_t off_e2     = 0;
    const size_t off_sedge  = off_e2 + mat_bytes;
    const size_t off_svc    = off_sedge + edge8;
    const size_t off_srow   = off_svc + edge8;
    const size_t off_cnt    = off_srow + edge4;
    const size_t off_rowptr = off_cnt + node_ints;
    const size_t off_tails  = off_rowptr + rp_bytes;
    const size_t off_bsums  = off_tails + ((NBKT + 255) & ~255) * sizeof(int);
    const size_t off_boffs  = off_bsums + 1024;
    const size_t required   = off_boffs + 1024;

    const int edge_blocks  = (N_EDGES + 255) / 256;
    const int dense_blocks = (N_NODES + 15) / 16;
    const int spmm_blocks  = (N_NODES + 3) / 4;

    if (ws_size >= required) {
        float*  e2      = (float*)((char*)d_ws + off_e2);
        float2* sedge   = (float2*)((char*)d_ws + off_sedge);
        float2* svc     = (float2*)((char*)d_ws + off_svc);
        int*    srow    = (int*)((char*)d_ws + off_srow);
        int*    cnt     = (int*)((char*)d_ws + off_cnt);
        int*    row_ptr = (int*)((char*)d_ws + off_rowptr);
        int*    tails   = (int*)((char*)d_ws + off_tails);
        int*    bsums   = (int*)((char*)d_ws + off_bsums);
        int*    boffs   = (int*)((char*)d_ws + off_boffs);

        // CSR build (once, reused by both SpMMs)
        hipMemsetAsync(cnt, 0, node_ints, stream);
        hist_kernel<<<edge_blocks, 256, 0, stream>>>(adj_rows, cnt);
        scan_partial<<<NBLK, 256, 0, stream>>>(cnt, bsums);
        scan_blk<<<1, 256, 0, stream>>>(bsums, boffs);
        scan_apply<<<NBLK, 256, 0, stream>>>(cnt, boffs, row_ptr);
        init_aux<<<(NBKT + 255) / 256, 256, 0, stream>>>(row_ptr, tails);

        // two-level edge sort
        partition_l1<<<NBLK_L1, 256, 0, stream>>>(
            adj_vals, adj_rows, adj_cols, tails, svc, srow);
        place_l2<<<NBKT, 256, 0, stream>>>(row_ptr, srow, svc, sedge);

        // fused stages
        spmm_fused<true><<<spmm_blocks, 256, 0, stream>>>(
            row_ptr, sedge, user_emb, item_emb, W0, e2, out);
        spmm_fused<false><<<spmm_blocks, 256, 0, stream>>>(
            row_ptr, sedge, e2, nullptr, W1, nullptr, out);
    } else {
        // fallback: round-1 atomic path
        float* t  = (float*)d_ws;
        float* e2 = (float*)((char*)d_ws + mat_bytes);

        hipMemsetAsync(t, 0, mat_bytes, stream);
        spmm_atomic<<<(N_EDGES + 3) / 4, 256, 0, stream>>>(
            adj_vals, adj_rows, adj_cols, user_emb, item_emb, t);
        dense_stage<true><<<dense_blocks, 256, 0, stream>>>(
            t, W0, user_emb, item_emb, e2, out);

        hipMemsetAsync(t, 0, mat_bytes, stream);
        spmm_atomic<<<(N_EDGES + 3) / 4, 256, 0, stream>>>(
            adj_vals, adj_rows, adj_cols, e2, nullptr, t);
        dense_stage<false><<<dense_blocks, 256, 0, stream>>>(
            t, W1, nullptr, nullptr, nullptr, out);
    }
}